// Round 1
// 189.605 us; speedup vs baseline: 1.0006x; 1.0006x over previous
//
#include <hip/hip_runtime.h>

// Trilinear 3D warp: out[b,x,y,z] = trilerp(image[b], (x,y,z) + ddf[b,x,y,z,:])
// Dims fixed: B=4, F=M=(128,128,128).
// R6: (a) constant-offset corner reads: when ix0==127 (resp. y,z) the upper
//     weight is exactly 0, so the +1 corner can be read unconditionally ->
//     corners at la + {0,1,28,29,700,701,728,729} -> 4x ds_read2_b32, no i1
//     clamps, no per-corner address math. Junk overreads stay inside padded,
//     staged-finite LDS and are multiplied by 0.
//     (b) 16x16x16 tile / 1024-thread block: region 25x25x28 (PLANE=700),
//     padded RSZ=18432 floats = 72KB -> 2 blocks/CU = 32 waves (100% cap),
//     staged traffic 4.3 floats/voxel (-26% vs R5).
// R7: VALU trim (~25%) with identical structure:
//     (a) block-uniform in-bounds: the edge-OR rescue (ex & ix0==127) is
//         exactly "bound+1", so inX = (unsigned)ox <= (RXT-2 + ex) with a
//         scalar bound -> 3 v_cmp + s_and instead of ~11 per-lane ops.
//     (b) wx1 = v_fract_f32(lx), ix0 = (int)lx (trunc==floor for lx>=0):
//         drops v_floor per axis.
//     (c) packed-f32 lerp: corners paired along z == ds_read2_b32 dest pairs
//         (mov-free); lerp y then x as 2-wide v_pk_fma_f32, z last scalar:
//         14 VALU -> 8.
//     (d) (ox&31)*PLANE etc -> v_mad_u32_u24 (full-rate) instead of
//         quarter-rate v_mul_lo_u32.

#define DIM 128
#define HALO 4
#define RXT 25            // 16 + 2*4 + 1
#define RYT 25
#define ZP  28            // logical 25, padded to mult-of-4 (all rows real)
#define PLANE (RYT * ZP)  // 700
#define REAL  (RXT * PLANE) // 17500
#define RSZ  18432        // pad past max overhang 17499+729; 72KB LDS

typedef float f2 __attribute__((ext_vector_type(2)));

__global__ __launch_bounds__(1024, 8) void warp_kernel(
    const float* __restrict__ ddf,
    const float* __restrict__ image,
    float* __restrict__ out)
{
    __shared__ float tile[RSZ];

    int bid = blockIdx.x;
    int zt = bid & 7;
    int yt = (bid >> 3) & 7;
    int xt = (bid >> 6) & 7;
    int b  = bid >> 9;

    int x0 = xt << 4, y0 = yt << 4, z0 = zt << 4;

    // Slide region into bounds; rz0 stays a multiple of 4 -> 16B chunks aligned.
    int rx0 = min(max(x0 - HALO, 0), DIM - RXT);   // <= 103
    int ry0 = min(max(y0 - HALO, 0), DIM - RYT);   // <= 103
    int rz0 = min(max(z0 - HALO, 0), DIM - ZP);    // <= 100, mult of 4

    int tid = threadIdx.x;

    // Lane-along-z mapping; thread's 4 voxels strided in x by 4.
    int zs = tid & 15;
    int yy = (tid >> 4) & 15;
    int xp = tid >> 8;              // 0..3

    int x = x0 + xp;
    int y = y0 + yy;
    int z = z0 + zs;
    int vbase = (b << 21) + (x << 14) + (y << 7) + z;

    // Preload all 12 ddf components (independent of staging; overlaps it).
    float d0[4], d1[4], d2[4];
#pragma unroll
    for (int j = 0; j < 4; ++j) {
        const float* dp = ddf + (size_t)3 * (unsigned)(vbase + ((j << 2) << 14));
        d0[j] = __builtin_nontemporal_load(dp);
        d1[j] = __builtin_nontemporal_load(dp + 1);
        d2[j] = __builtin_nontemporal_load(dp + 2);
    }

    const float* img = image + ((size_t)b << 21);

    // Stage region: 5 iters x 1024 threads x 16B direct global->LDS.
    {
        int base0 = (rx0 << 14) + (ry0 << 7) + rz0;
        int t4 = tid << 2;
#pragma unroll
        for (int k = 0; k < 5; ++k) {
            int i = (k << 12) + t4;
            if (i < RSZ) {
                int rx  = i / PLANE;
                int rem = i - rx * PLANE;
                int ry  = rem / ZP;
                int rz  = rem - ry * ZP;
                int goff = base0 + (rx << 14) + (ry << 7) + rz;
                goff = min(goff, (1 << 21) - 4);  // junk tail stays in-bounds
                __builtin_amdgcn_global_load_lds(
                    (const __attribute__((address_space(1))) void*)(img + goff),
                    (__attribute__((address_space(3))) void*)(tile + i),
                    16, 0, 0);
            }
        }
    }
    __syncthreads();

    const float maxf = (float)(DIM - 1);
    // Block-uniform in-bounds upper bounds. At a slid-to-edge region the
    // ix0==DIM-1 case has upper weight exactly 0, and ox==RXT-1 occurs ONLY
    // there, so the edge-OR rescue is equivalent to raising the bound by 1.
    unsigned ubx = (unsigned)(RXT - 2 + (rx0 == DIM - RXT));
    unsigned uby = (unsigned)(RYT - 2 + (ry0 == DIM - RYT));
    unsigned ubz = (unsigned)(26      + (rz0 == DIM - ZP));

#pragma unroll
    for (int j = 0; j < 4; ++j) {
        int xj = x + (j << 2);
        float lx = (float)xj + d0[j];
        float ly = (float)y  + d1[j];
        float lz = (float)z  + d2[j];
        lx = fminf(fmaxf(lx, 0.0f), maxf);
        ly = fminf(fmaxf(ly, 0.0f), maxf);
        lz = fminf(fmaxf(lz, 0.0f), maxf);
        // lx,ly,lz >= 0 -> trunc == floor; fract gives the upper weight.
        int ix0 = (int)lx, iy0 = (int)ly, iz0 = (int)lz;
        float wx1 = __builtin_amdgcn_fractf(lx);
        float wy1 = __builtin_amdgcn_fractf(ly);
        float wz1 = __builtin_amdgcn_fractf(lz);

        int ox = ix0 - rx0, oy = iy0 - ry0, oz = iz0 - rz0;
        bool in = ((unsigned)ox <= ubx) & ((unsigned)oy <= uby) |
                  false;  // placeholder to keep short-circuit off
        in = (((unsigned)ox <= ubx) & ((unsigned)oy <= uby)) & ((unsigned)oz <= ubz);

        // Corner pairs along z: exactly the ds_read2_b32 destination pairs.
        // pXY = {c(X)(Y)0, c(X)(Y)1}   (X = +x corner bit, Y = +y corner bit)
        f2 p00, p01, p10, p11;
        if (in) {
            // &31 masks are no-ops in-range but prove 24-bit operands ->
            // full-rate v_mad_u32_u24 instead of quarter-rate v_mul_lo_u32.
            int la = (ox & 31) * PLANE + (oy & 31) * ZP + oz;
            p00.x = tile[la];              p00.y = tile[la + 1];
            p01.x = tile[la + ZP];         p01.y = tile[la + ZP + 1];
            p10.x = tile[la + PLANE];      p10.y = tile[la + PLANE + 1];
            p11.x = tile[la + PLANE + ZP]; p11.y = tile[la + PLANE + ZP + 1];
        } else {
            // Rare (|d| > halo) fallback: direct global gather with clamps.
            int ix1 = min(ix0 + 1, DIM - 1);
            int iy1 = min(iy0 + 1, DIM - 1);
            int iz1 = min(iz0 + 1, DIM - 1);
            int bx0 = ix0 << 14, bx1 = ix1 << 14;
            int by0 = iy0 << 7,  by1 = iy1 << 7;
            p00.x = img[bx0 + by0 + iz0]; p00.y = img[bx0 + by0 + iz1];
            p01.x = img[bx0 + by1 + iz0]; p01.y = img[bx0 + by1 + iz1];
            p10.x = img[bx1 + by0 + iz0]; p10.y = img[bx1 + by0 + iz1];
            p11.x = img[bx1 + by1 + iz0]; p11.y = img[bx1 + by1 + iz1];
        }

        // Packed lerp: y then x as 2-wide (v_pk_add/v_pk_fma), z last scalar.
        f2 wyv = {wy1, wy1};
        f2 wxv = {wx1, wx1};
        f2 q0 = p00 + (p01 - p00) * wyv;   // x=0, z in {0,1}
        f2 q1 = p10 + (p11 - p10) * wyv;   // x=1, z in {0,1}
        f2 e  = q0 + (q1 - q0) * wxv;      // z in {0,1}
        float r = __builtin_fmaf(wz1, e.y - e.x, e.x);

        __builtin_nontemporal_store(r, out + vbase + ((j << 2) << 14));
    }
}

extern "C" void kernel_launch(void* const* d_in, const int* in_sizes, int n_in,
                              void* d_out, int out_size, void* d_ws, size_t ws_size,
                              hipStream_t stream) {
    const float* ddf   = (const float*)d_in[0];
    const float* image = (const float*)d_in[1];
    float* out = (float*)d_out;

    // 4 batches * 8^3 tiles of 16^3 = 2048 blocks
    int grid = 4 * 8 * 8 * 8;
    warp_kernel<<<grid, 1024, 0, stream>>>(ddf, image, out);
}